// Round 4
// baseline (90.049 us; speedup 1.0000x reference)
//
#include <hip/hip_runtime.h>
#include <hip/hip_bf16.h>

#define C_IN    64
#define C_OUT   128
#define HH      112
#define WW      112
#define NB      16
#define KTOT    576      // C_IN * 9
#define TY      8
#define TX      16
#define HALO_Y  10
#define HALO_X  18
#define HALO_P  (HALO_Y*HALO_X)        // 180 halo pixels
#define NSTEPS  36       // KTOT / 16
#define TILES_X 7
#define TILES_Y 14
#define NTILES  (TILES_X*TILES_Y)      // 98
#define PH      114                    // padded spatial dim
#define PPIX    (PH*PH)                // 12996 padded pixels
#define XT_OFF  147456                 // bytes: pw occupies [0, 147456)
#define XT_BYTES ((size_t)NB * PPIX * C_IN * 2)

typedef __bf16 bf16x8 __attribute__((ext_vector_type(8)));
typedef float  f32x16 __attribute__((ext_vector_type(16)));

static __device__ __forceinline__ unsigned short f2bf(float v) {
    unsigned int u = __builtin_bit_cast(unsigned int, v);
    u = u + 0x7fffu + ((u >> 16) & 1u);   // RNE
    return (unsigned short)(u >> 16);
}

// ---------------- pack spW = weight*mask into bf16 MFMA A-fragments ----------------
// pw_frag[t][mt][lane] = 16 B (8 bf16); k_log(t,g,e)=t*16+g*8+e; ij=k_log>>6, c=k_log&63; k_orig=c*9+ij
__global__ __launch_bounds__(256) void pack_w_kernel(
        const float* __restrict__ weight, const float* __restrict__ mask,
        unsigned short* __restrict__ pw) {
    int t  = blockIdx.x;           // 0..35
    int mt = threadIdx.x >> 6;     // 0..3
    int l  = threadIdx.x & 63;
    int g  = l >> 5;
    int m  = mt * 32 + (l & 31);
    unsigned int words[4];
    #pragma unroll
    for (int ew = 0; ew < 4; ++ew) {
        unsigned int w2[2];
        #pragma unroll
        for (int h = 0; h < 2; ++h) {
            int e    = ew * 2 + h;
            int klog = t * 16 + g * 8 + e;
            int ij   = klog >> 6;
            int c    = klog & 63;
            int ko   = c * 9 + ij;
            w2[h] = f2bf(weight[m * KTOT + ko] * mask[m * KTOT + ko]);
        }
        words[ew] = w2[0] | (w2[1] << 16);
    }
    uint4 o4; o4.x = words[0]; o4.y = words[1]; o4.z = words[2]; o4.w = words[3];
    ((uint4*)pw)[(t * 4 + mt) * 64 + l] = o4;
}

// ---------------- pre-pass: x [b][c][h][w] fp32 -> xT [b][hp][wp][c] bf16, zero-padded ----------------
// XCD-pinned: image b is processed by blocks whose hardware XCD (blockIdx%8) == b/2,
// matching the conv kernel's bijective swizzle (conv image b reads on XCD b/2).
__global__ __launch_bounds__(256) void transpose_x_kernel(
        const float* __restrict__ x, unsigned short* __restrict__ xT) {
    const int f = blockIdx.x;          // 0..815 ; XCD = f & 7 (816 % 8 == 0)
    const int k = f & 7, j = f >> 3;   // j: 0..101  (102 chunks per XCD = 2 images)
    const int b = 2 * k + (j >= 51);
    const int pp = (j % 51) * 256 + threadIdx.x;
    if (pp >= PPIX) return;
    const int hp = pp / PH, wp = pp - hp * PH;
    const int gh = hp - 1, gw = wp - 1;
    const bool valid = (unsigned)gh < (unsigned)HH && (unsigned)gw < (unsigned)WW;
    const float* src = x + (size_t)b * C_IN * (HH * WW) + (gh * WW + gw);
    uint4* dst = (uint4*)(xT + ((size_t)b * PPIX + pp) * C_IN);
    #pragma unroll
    for (int cb = 0; cb < 8; ++cb) {
        unsigned int w4[4];
        #pragma unroll
        for (int h = 0; h < 4; ++h) {
            float v0 = valid ? src[(size_t)(cb * 8 + h * 2    ) * (HH * WW)] : 0.0f;
            float v1 = valid ? src[(size_t)(cb * 8 + h * 2 + 1) * (HH * WW)] : 0.0f;
            w4[h] = (unsigned)f2bf(v0) | ((unsigned)f2bf(v1) << 16);
        }
        uint4 o; o.x = w4[0]; o.y = w4[1]; o.z = w4[2]; o.w = w4[3];
        dst[cb] = o;
    }
}

// ---------------- main conv: staged LDS B + depth-2 software-pipelined A ----------------
__global__ __launch_bounds__(256, 4) void sparse_conv_xt_kernel(
        const unsigned short* __restrict__ xT, const unsigned short* __restrict__ pw,
        const float* __restrict__ bias, float* __restrict__ out) {
    __shared__ __align__(16) unsigned short xs[1536 * 8];   // 24576 B

    // XCD-bijective swizzle: 1568 % 8 == 0; XCD k gets 196 contiguous logical tiles (2 images)
    const int bid = (blockIdx.x & 7) * (NB * NTILES / 8) + (blockIdx.x >> 3);
    const int b   = bid / NTILES;
    const int t98 = bid % NTILES;
    const int tyi = t98 / TILES_X;
    const int txi = t98 % TILES_X;
    const int h0  = tyi * TY, w0 = txi * TX;
    const int tid = threadIdx.x;
    const int wave = tid >> 6, l = tid & 63;
    const int wm = wave >> 1, wn = wave & 1;
    const int g  = l >> 5,  ln = l & 31;

    // ---- stage halo: 6 rounds of global_load_lds dwordx4, linear LDS dest, swizzled source ----
    {
        const char* xTb = (const char*)xT + (size_t)b * PPIX * (C_IN * 2);
        #pragma unroll
        for (int r = 0; r < 6; ++r) {
            int chunk = r * 256 + tid;          // 16B chunk index = p*8 + slot
            int p = chunk >> 3; if (p > HALO_P - 1) p = HALO_P - 1;   // clamp tail
            int s = chunk & 7;
            int yy = p / HALO_X, xx = p - yy * HALO_X;
            int hp = h0 + yy, wp = w0 + xx;     // padded coords (halo -1 absorbed by pad)
            const char* gp = xTb + (size_t)(hp * PH + wp) * (C_IN * 2) + (((s ^ p) & 7) << 4);
            char* lp = (char*)xs + r * 4096 + wave * 1024;   // + lane*16 done by HW
            __builtin_amdgcn_global_load_lds(
                (const __attribute__((address_space(1))) void*)gp,
                (__attribute__((address_space(3))) void*)lp, 16, 0, 0);
        }
    }

    const uint4* __restrict__ pwv = (const uint4*)pw;

    // ---- A prologue: issue t=0,1 fragments before the barrier (arrive during drain) ----
    uint4 Abuf[2][2];
    Abuf[0][0] = pwv[(0 * 4 + wm * 2 + 0) * 64 + l];
    Abuf[0][1] = pwv[(0 * 4 + wm * 2 + 1) * 64 + l];
    Abuf[1][0] = pwv[(1 * 4 + wm * 2 + 0) * 64 + l];
    Abuf[1][1] = pwv[(1 * 4 + wm * 2 + 1) * 64 + l];

    __syncthreads();

    int P0[2];
    #pragma unroll
    for (int ntp = 0; ntp < 2; ++ntp) {
        int pt = wn * 64 + ntp * 32 + ln;   // pixel index in 8x16 tile
        P0[ntp] = (pt >> 4) * HALO_X + (pt & 15);
    }

    f32x16 acc[2][2];
    #pragma unroll
    for (int i = 0; i < 2; ++i)
        #pragma unroll
        for (int jq = 0; jq < 2; ++jq)
            #pragma unroll
            for (int q = 0; q < 16; ++q) acc[i][jq][q] = 0.0f;

    // ---- K loop: t = ij*4 + cs, fully unrolled, depth-2 A prefetch ----
    #pragma unroll
    for (int t = 0; t < NSTEPS; ++t) {
        const int ij = t >> 2, cs = t & 3;
        const int di = ij / 3, dj = ij - di * 3;
        const int pa = t & 1;
        uint4 au0 = Abuf[pa][0], au1 = Abuf[pa][1];
        if (t + 2 < NSTEPS) {
            Abuf[pa][0] = pwv[((t + 2) * 4 + wm * 2 + 0) * 64 + l];
            Abuf[pa][1] = pwv[((t + 2) * 4 + wm * 2 + 1) * 64 + l];
        }
        const int P0a = P0[0] + di * HALO_X + dj;
        const int P1a = P0[1] + di * HALO_X + dj;
        const int jb  = cs * 2 + g;   // 16B channel-block index
        bf16x8 b0 = __builtin_bit_cast(bf16x8,
            *(const uint4*)((const char*)xs + P0a * (C_IN * 2) + (((jb ^ P0a) & 7) << 4)));
        bf16x8 b1 = __builtin_bit_cast(bf16x8,
            *(const uint4*)((const char*)xs + P1a * (C_IN * 2) + (((jb ^ P1a) & 7) << 4)));
        bf16x8 a0 = __builtin_bit_cast(bf16x8, au0);
        bf16x8 a1 = __builtin_bit_cast(bf16x8, au1);
        acc[0][0] = __builtin_amdgcn_mfma_f32_32x32x16_bf16(a0, b0, acc[0][0], 0, 0, 0);
        acc[0][1] = __builtin_amdgcn_mfma_f32_32x32x16_bf16(a0, b1, acc[0][1], 0, 0, 0);
        acc[1][0] = __builtin_amdgcn_mfma_f32_32x32x16_bf16(a1, b0, acc[1][0], 0, 0, 0);
        acc[1][1] = __builtin_amdgcn_mfma_f32_32x32x16_bf16(a1, b1, acc[1][1], 0, 0, 0);
    }

    // ---- epilogue: C/D layout col=lane&31 (pixel), row=(r&3)+8*(r>>2)+4*(lane>>5) ----
    const size_t outb = (size_t)b * C_OUT * HH * WW;
    #pragma unroll
    for (int mtp = 0; mtp < 2; ++mtp) {
        #pragma unroll
        for (int r = 0; r < 16; ++r) {
            int mloc = (r & 3) + 8 * (r >> 2) + 4 * g;
            int o = (wm * 2 + mtp) * 32 + mloc;
            float bv = bias[o];
            #pragma unroll
            for (int ntp = 0; ntp < 2; ++ntp) {
                int p  = wn * 64 + ntp * 32 + ln;
                int gh = h0 + (p >> 4), gw = w0 + (p & 15);
                out[outb + ((size_t)o * HH + gh) * WW + gw] = acc[mtp][ntp][r] + bv;
            }
        }
    }
}

// ---------------- fallback (round-2 kernel) if ws too small for xT ----------------
__global__ __launch_bounds__(256, 4) void sparse_conv_fb_kernel(
        const float* __restrict__ x, const unsigned short* __restrict__ pw,
        const float* __restrict__ bias, float* __restrict__ out) {
    __shared__ __align__(16) unsigned short xs[HALO_P * C_IN];

    const int bid = blockIdx.x;
    const int b   = bid / NTILES;
    const int t98 = bid % NTILES;
    const int tyi = t98 / TILES_X;
    const int txi = t98 % TILES_X;
    const int h0  = tyi * TY, w0 = txi * TX;
    const int tid = threadIdx.x;

    const float* xb = x + (size_t)b * C_IN * HH * WW;
    {
        const int p  = tid;
        const bool act = p < HALO_P;
        int yy = p / HALO_X;
        int xx = p - yy * HALO_X;
        int gh = h0 + yy - 1, gw = w0 + xx - 1;
        const bool valid = act && (unsigned)gh < (unsigned)HH && (unsigned)gw < (unsigned)WW;
        const float* bp = xb + (gh * WW + gw);
        float v[C_IN];
        #pragma unroll
        for (int c = 0; c < C_IN; ++c)
            v[c] = valid ? bp[c * (HH * WW)] : 0.0f;
        if (act) {
            char* xc = (char*)xs + p * (C_IN * 2);
            #pragma unroll
            for (int j = 0; j < 8; ++j) {
                bf16x8 bv;
                #pragma unroll
                for (int e = 0; e < 8; ++e) bv[e] = (__bf16)v[j * 8 + e];
                *(uint4*)(xc + (((j ^ p) & 7) << 4)) = __builtin_bit_cast(uint4, bv);
            }
        }
    }
    __syncthreads();

    const int wave = tid >> 6, l = tid & 63;
    const int wm = wave >> 1, wn = wave & 1;
    const int g  = l >> 5,  ln = l & 31;

    int P0[2];
    #pragma unroll
    for (int ntp = 0; ntp < 2; ++ntp) {
        int pt = wn * 64 + ntp * 32 + ln;
        P0[ntp] = (pt >> 4) * HALO_X + (pt & 15);
    }

    f32x16 acc[2][2];
    #pragma unroll
    for (int i = 0; i < 2; ++i)
        #pragma unroll
        for (int jq = 0; jq < 2; ++jq)
            #pragma unroll
            for (int q = 0; q < 16; ++q) acc[i][jq][q] = 0.0f;

    const uint4* __restrict__ pwv = (const uint4*)pw;

    #pragma unroll 1
    for (int ij = 0; ij < 9; ++ij) {
        const int di = ij / 3;
        const int dj = ij - di * 3;
        const int P0a = P0[0] + di * HALO_X + dj;
        const int P1a = P0[1] + di * HALO_X + dj;
        #pragma unroll
        for (int cs = 0; cs < 4; ++cs) {
            const int t = ij * 4 + cs;
            bf16x8 a0 = __builtin_bit_cast(bf16x8, pwv[(t * 4 + wm * 2 + 0) * 64 + l]);
            bf16x8 a1 = __builtin_bit_cast(bf16x8, pwv[(t * 4 + wm * 2 + 1) * 64 + l]);
            const int jb = cs * 2 + g;
            bf16x8 b0 = __builtin_bit_cast(bf16x8,
                *(const uint4*)((const char*)xs + P0a * (C_IN * 2) + (((jb ^ P0a) & 7) << 4)));
            bf16x8 b1 = __builtin_bit_cast(bf16x8,
                *(const uint4*)((const char*)xs + P1a * (C_IN * 2) + (((jb ^ P1a) & 7) << 4)));
            acc[0][0] = __builtin_amdgcn_mfma_f32_32x32x16_bf16(a0, b0, acc[0][0], 0, 0, 0);
            acc[0][1] = __builtin_amdgcn_mfma_f32_32x32x16_bf16(a0, b1, acc[0][1], 0, 0, 0);
            acc[1][0] = __builtin_amdgcn_mfma_f32_32x32x16_bf16(a1, b0, acc[1][0], 0, 0, 0);
            acc[1][1] = __builtin_amdgcn_mfma_f32_32x32x16_bf16(a1, b1, acc[1][1], 0, 0, 0);
        }
    }

    const size_t outb = (size_t)b * C_OUT * HH * WW;
    #pragma unroll
    for (int mtp = 0; mtp < 2; ++mtp) {
        #pragma unroll
        for (int r = 0; r < 16; ++r) {
            int mloc = (r & 3) + 8 * (r >> 2) + 4 * g;
            int o = (wm * 2 + mtp) * 32 + mloc;
            float bv = bias[o];
            #pragma unroll
            for (int ntp = 0; ntp < 2; ++ntp) {
                int p  = wn * 64 + ntp * 32 + ln;
                int gh = h0 + (p >> 4), gw = w0 + (p & 15);
                out[outb + ((size_t)o * HH + gh) * WW + gw] = acc[mtp][ntp][r] + bv;
            }
        }
    }
}

extern "C" void kernel_launch(void* const* d_in, const int* in_sizes, int n_in,
                              void* d_out, int out_size, void* d_ws, size_t ws_size,
                              hipStream_t stream) {
    const float* x    = (const float*)d_in[0];
    const float* w    = (const float*)d_in[1];
    const float* mk   = (const float*)d_in[2];
    const float* bs   = (const float*)d_in[3];
    float* out        = (float*)d_out;
    unsigned short* pw = (unsigned short*)d_ws;   // [0, 147456)

    pack_w_kernel<<<dim3(NSTEPS), dim3(256), 0, stream>>>(w, mk, pw);

    if (ws_size >= (size_t)XT_OFF + XT_BYTES) {
        unsigned short* xT = (unsigned short*)((char*)d_ws + XT_OFF);
        transpose_x_kernel<<<dim3(816), dim3(256), 0, stream>>>(x, xT);
        sparse_conv_xt_kernel<<<dim3(NB * NTILES), dim3(256), 0, stream>>>(xT, pw, bs, out);
    } else {
        sparse_conv_fb_kernel<<<dim3(NB * NTILES), dim3(256), 0, stream>>>(x, pw, bs, out);
    }
}